// Round 16
// baseline (73.288 us; speedup 1.0000x reference)
//
#include <hip/hip_runtime.h>

#define DIMV 16
#define NSTEP 4095      // 4096 - 1 increments
#define NC 64           // chunks
#define TSTEP 64        // chunk length
#define SIG13 4368      // 16 + 256 + 4096
#define L4 65536        // 16^4

// 16-wide register vector as explicit float4s — never runtime-indexed (rule #20).
struct V16 { float4 a, b, c, d; };

#define EACH(OP) OP(a,x) OP(a,y) OP(a,z) OP(a,w) OP(b,x) OP(b,y) OP(b,z) OP(b,w) \
                 OP(c,x) OP(c,y) OP(c,z) OP(c,w) OP(d,x) OP(d,y) OP(d,z) OP(d,w)

__device__ inline V16 ldv16(const float* p) {
    const float4* q = reinterpret_cast<const float4*>(p);
    V16 v; v.a = q[0]; v.b = q[1]; v.c = q[2]; v.d = q[3]; return v;
}
__device__ inline void stv16(float* p, const V16& v) {
    float4* q = reinterpret_cast<float4*>(p);
    q[0] = v.a; q[1] = v.b; q[2] = v.c; q[3] = v.d;
}
__device__ inline V16 zerov16() {
    V16 v; v.a = v.b = v.c = v.d = make_float4(0.f, 0.f, 0.f, 0.f); return v;
}

// ------------- per-chunk LOCAL signature (levels 1-3) + fused dx -------------
// (R12-proven, unchanged)
__global__ __launch_bounds__(256, 1) void k_chunk_sig(const float* __restrict__ x,
                                                      float* __restrict__ dx,
                                                      float* __restrict__ chunk_sig) {
    const int cb = blockIdx.x;
    const int t = threadIdx.x;
    const int ia = t >> 4, ib = t & 15;
    float A1a = 0.f, A2 = 0.f;
    V16 A3 = zerov16();

    const int s0 = cb * TSTEP;
    const int s1 = (s0 + TSTEP < NSTEP) ? (s0 + TSTEP) : NSTEP;

    const float* r0 = x + (size_t)s0 * DIMV;
    const float* r1 = x + (size_t)(s0 + 1) * DIMV;
    V16 xprev = ldv16(r0);
    float xpa = r0[ia], xpb = r0[ib];
    V16 xcur = ldv16(r1);
    float xca = r1[ia], xcb = r1[ib];

    for (int s = s0; s < s1; ++s) {
        int sp = (s + 2 <= NSTEP) ? (s + 2) : NSTEP;
        const float* rn = x + (size_t)sp * DIMV;
        V16 xnext = ldv16(rn);
        float xna = rn[ia], xnb = rn[ib];

        V16 dxv;
#define SB(Q,C) dxv.Q.C = xcur.Q.C - xprev.Q.C;
        EACH(SB)
#undef SB
        float dxa = xca - xpa;
        float dxb = xcb - xpb;
        stv16(dx + (size_t)s * DIMV, dxv);

        float V2 = fmaf(dxb, fmaf(dxa, 1.f/6.f, 0.5f * A1a), A2);
        float h2 = fmaf(dxa, 0.5f, A1a);
#define CS(Q,C) A3.Q.C = fmaf(dxv.Q.C, V2, A3.Q.C);
        EACH(CS)
#undef CS
        A2 = fmaf(dxb, h2, A2);
        A1a += dxa;

        xprev = xcur; xpa = xca; xpb = xcb;
        xcur = xnext; xca = xna; xcb = xnb;
    }
    float* o = chunk_sig + (size_t)cb * SIG13;
    if (ib == 0) o[ia] = A1a;
    o[16 + t] = A2;
    stv16(o + 272 + t * 16, A3);
}

// ------------- fused cascaded prefix (levels 1,2,3) -------------
// (R12-proven, unchanged)
__global__ __launch_bounds__(256, 1) void k_prefixB(const float* __restrict__ chunk_sig,
                                                    float* __restrict__ prefix_sig,
                                                    float* __restrict__ out13) {
    __shared__ float s1s[NC][16];
    __shared__ float p1s[NC][16];
    __shared__ float p2s[NC][16];
    const int a = blockIdx.x;
    const int t = threadIdx.x;

    for (int base = 0; base < NC; base += 16) {
        int c = base + (t >> 4);
        s1s[c][t & 15] = chunk_sig[(size_t)c * SIG13 + (t & 15)];
    }
    __syncthreads();
    if (t < 16) {
        float p = 0.f;
        for (int c = 0; c < NC; ++c) {
            p1s[c][t] = p;
            if (a == 0) prefix_sig[(size_t)c * SIG13 + t] = p;
            p += s1s[c][t];
        }
        if (a == 0) out13[t] = p;
    }
    __syncthreads();
    {
        const int aa = t >> 4, bb = t & 15;
        float pl0 = chunk_sig[0ul * SIG13 + 16 + t];
        float pl1 = chunk_sig[1ul * SIG13 + 16 + t];
        float pl2 = chunk_sig[2ul * SIG13 + 16 + t];
        float pl3 = chunk_sig[3ul * SIG13 + 16 + t];
        float pl4 = chunk_sig[4ul * SIG13 + 16 + t];
        float pl5 = chunk_sig[5ul * SIG13 + 16 + t];
        float pl6 = chunk_sig[6ul * SIG13 + 16 + t];
        float pl7 = chunk_sig[7ul * SIG13 + 16 + t];
        float p = 0.f;
        for (int cb2 = 0; cb2 < NC; cb2 += 8) {
#define STEP2(J) { int c = cb2 + J; \
            if (aa == a) p2s[c][bb] = p; \
            if (a == 0) prefix_sig[(size_t)c * SIG13 + 16 + t] = p; \
            p = fmaf(p1s[c][aa], s1s[c][bb], p + pl##J); \
            int cn = c + 8; \
            if (cn < NC) pl##J = chunk_sig[(size_t)cn * SIG13 + 16 + t]; }
            STEP2(0) STEP2(1) STEP2(2) STEP2(3) STEP2(4) STEP2(5) STEP2(6) STEP2(7)
#undef STEP2
        }
        if (a == 0) out13[16 + t] = p;
    }
    __syncthreads();
    {
        const int c3 = t & 15, k = t >> 4;
        const size_t off3 = 272 + (size_t)a * 256 + t;
#define LD3(J, C) \
        float l3_##J = chunk_sig[(size_t)(C) * SIG13 + off3]; \
        float l2_##J = chunk_sig[(size_t)(C) * SIG13 + 16 + t];
        LD3(0,0) LD3(1,1) LD3(2,2) LD3(3,3) LD3(4,4) LD3(5,5) LD3(6,6) LD3(7,7)
#undef LD3
        float p = 0.f;
        for (int cb2 = 0; cb2 < NC; cb2 += 8) {
#define STEP3(J) { int c = cb2 + J; \
            prefix_sig[(size_t)c * SIG13 + off3] = p; \
            p = p + l3_##J + fmaf(p1s[c][a], l2_##J, p2s[c][k] * s1s[c][c3]); \
            int cn = c + 8; \
            if (cn < NC) { \
                l3_##J = chunk_sig[(size_t)cn * SIG13 + off3]; \
                l2_##J = chunk_sig[(size_t)cn * SIG13 + 16 + t]; } }
            STEP3(0) STEP3(1) STEP3(2) STEP3(3) STEP3(4) STEP3(5) STEP3(6) STEP3(7)
#undef STEP3
        }
        out13[off3] = p;
    }
}

// ------------- level-4 accumulation: j-SINGLE split, 2x unrolled -------------
// block (cb, j): chunk cb (64 steps), single third-index j. Per-thread state:
// acc V16 + A3 scalar + two statically-named row buffers (no cur<-nxt rotation).
// ~75 VGPR target; 1024 blocks = 4 blocks/CU = 4 waves/SIMD latency hiding.
// No __launch_bounds__ (every bounded variant since R3 ran ~30 us at VGPR 28).
__global__ void k_scan4(const float* __restrict__ dx,
                        const float* __restrict__ prefix_sig,
                        float* __restrict__ dst) {
    const int cb = blockIdx.x;   // 0..NC-1
    const int j = blockIdx.y;    // 0..15 : third index
    const int t = threadIdx.x;
    const int ia = t >> 4, ib = t & 15;

    const float* P = prefix_sig + (size_t)cb * SIG13;
    float A1a = P[ia];
    float A2 = P[16 + t];
    float A3s = P[272 + t * 16 + j];
    V16 acc = zerov16();

    const int s0 = cb * TSTEP;
    const int s1 = (s0 + TSTEP < NSTEP) ? (s0 + TSTEP) : NSTEP;

    // two statically-named buffers: vA = even rows, vB = odd rows
    const float* rA = dx + (size_t)s0 * DIMV;
    const float* rB = rA + DIMV;              // s0+1 <= 4033 < NSTEP always
    V16 vA = ldv16(rA); float aA = rA[ia], bA = rA[ib], jA = rA[j];
    V16 vB = ldv16(rB); float aB = rB[ia], bB = rB[ib], jB = rB[j];

    for (int s = s0; s < s1; s += 2) {
        // ---- step s (buffer A) ----
        {
            float U2 = fmaf(bA, fmaf(aA, 1.f/24.f, A1a * (1.f/6.f)), 0.5f * A2);
            float V2 = fmaf(bA, fmaf(aA, 1.f/6.f, A1a * 0.5f), A2);
            float h2 = fmaf(aA, 0.5f, A1a);
            float u3 = fmaf(jA, U2, A3s);
#define AC(Q,C) acc.Q.C = fmaf(u3, vA.Q.C, acc.Q.C);
            EACH(AC)
#undef AC
            A3s = fmaf(jA, V2, A3s);
            A2 = fmaf(bA, h2, A2);
            A1a += aA;
        }
        // prefetch row s+2 into A (clamped; dead at tail)
        {
            int sp = (s + 2 < s1) ? (s + 2) : s;
            const float* rn = dx + (size_t)sp * DIMV;
            vA = ldv16(rn); aA = rn[ia]; bA = rn[ib]; jA = rn[j];
        }
        // ---- step s+1 (buffer B; guarded for odd tail) ----
        if (s + 1 < s1) {
            float U2 = fmaf(bB, fmaf(aB, 1.f/24.f, A1a * (1.f/6.f)), 0.5f * A2);
            float V2 = fmaf(bB, fmaf(aB, 1.f/6.f, A1a * 0.5f), A2);
            float h2 = fmaf(aB, 0.5f, A1a);
            float u3 = fmaf(jB, U2, A3s);
#define AC(Q,C) acc.Q.C = fmaf(u3, vB.Q.C, acc.Q.C);
            EACH(AC)
#undef AC
            A3s = fmaf(jB, V2, A3s);
            A2 = fmaf(bB, h2, A2);
            A1a += aB;
        }
        // prefetch row s+3 into B (clamped; dead at tail)
        {
            int sp = (s + 3 < s1) ? (s + 3) : s;
            const float* rn = dx + (size_t)sp * DIMV;
            vB = ldv16(rn); aB = rn[ia]; bB = rn[ib]; jB = rn[j];
        }
    }

    float* o = dst + (size_t)cb * L4 + t * 256 + j * 16;
    stv16(o, acc);
}

// ------------- atomic fallback (separate plain kernel; only if ws too small) ----
__global__ void k_scan4_atomic(const float* __restrict__ dx,
                               const float* __restrict__ prefix_sig,
                               float* __restrict__ dst) {
    const int cb = blockIdx.x;
    const int j = blockIdx.y;
    const int t = threadIdx.x;
    const int ia = t >> 4, ib = t & 15;

    const float* P = prefix_sig + (size_t)cb * SIG13;
    float A1a = P[ia];
    float A2 = P[16 + t];
    float A3s = P[272 + t * 16 + j];
    V16 acc = zerov16();

    const int s0 = cb * TSTEP;
    const int s1 = (s0 + TSTEP < NSTEP) ? (s0 + TSTEP) : NSTEP;

    for (int s = s0; s < s1; ++s) {
        const float* row = dx + (size_t)s * DIMV;
        V16 cur = ldv16(row);
        float ca = row[ia], cbv = row[ib], cj = row[j];

        float U2 = fmaf(cbv, fmaf(ca, 1.f/24.f, A1a * (1.f/6.f)), 0.5f * A2);
        float V2 = fmaf(cbv, fmaf(ca, 1.f/6.f, A1a * 0.5f), A2);
        float h2 = fmaf(ca, 0.5f, A1a);
        float u3 = fmaf(cj, U2, A3s);
#define AC(Q,C) acc.Q.C = fmaf(u3, cur.Q.C, acc.Q.C);
        EACH(AC)
#undef AC
        A3s = fmaf(cj, V2, A3s);
        A2 = fmaf(cbv, h2, A2);
        A1a += ca;
    }

    float* o = dst + t * 256 + j * 16;
#define STA(Q,C,K) atomicAdd(o + (K), acc.Q.C);
    STA(a,x,0) STA(a,y,1) STA(a,z,2) STA(a,w,3)
    STA(b,x,4) STA(b,y,5) STA(b,z,6) STA(b,w,7)
    STA(c,x,8) STA(c,y,9) STA(c,z,10) STA(c,w,11)
    STA(d,x,12) STA(d,y,13) STA(d,z,14) STA(d,w,15)
#undef STA
}

// ------------- sum per-chunk level-4 partials (float2, 128 blocks) -------------
__global__ __launch_bounds__(256) void k_reduce4(const float* __restrict__ partials,
                                                 float* __restrict__ out4) {
    const int i2 = blockIdx.x * 256 + threadIdx.x;  // 0..32767 float2 slots
    const float2* p2 = reinterpret_cast<const float2*>(partials);
    float2 s = make_float2(0.f, 0.f);
#pragma unroll 8
    for (int c = 0; c < NC; ++c) {
        float2 v = p2[(size_t)c * (L4 / 2) + i2];
        s.x += v.x; s.y += v.y;
    }
    reinterpret_cast<float2*>(out4)[i2] = s;
}

extern "C" void kernel_launch(void* const* d_in, const int* in_sizes, int n_in,
                              void* d_out, int out_size, void* d_ws, size_t ws_size,
                              hipStream_t stream) {
    const float* x = (const float*)d_in[0];
    float* out = (float*)d_out;
    float* ws = (float*)d_ws;

    float* dx = ws;                                     // 65536 floats
    float* chunk_sig = ws + 65536;                      // NC * SIG13
    float* prefix_sig = chunk_sig + (size_t)NC * SIG13; // NC * SIG13
    float* partials = prefix_sig + (size_t)NC * SIG13;  // NC * L4
    const size_t need_bytes =
        ((size_t)65536 + 2ull * NC * SIG13 + (size_t)NC * L4) * sizeof(float);

    k_chunk_sig<<<dim3(NC), dim3(256), 0, stream>>>(x, dx, chunk_sig);
    k_prefixB<<<dim3(16), dim3(256), 0, stream>>>(chunk_sig, prefix_sig, out);

    if (ws_size >= need_bytes) {
        k_scan4<<<dim3(NC, 16), dim3(256), 0, stream>>>(dx, prefix_sig, partials);
        k_reduce4<<<dim3(128), dim3(256), 0, stream>>>(partials, out + SIG13);
    } else {
        hipMemsetAsync(out + SIG13, 0, (size_t)L4 * sizeof(float), stream);
        k_scan4_atomic<<<dim3(NC, 16), dim3(256), 0, stream>>>(dx, prefix_sig,
                                                               out + SIG13);
    }
}

// Round 17
// 59.834 us; speedup vs baseline: 1.2249x; 1.2249x over previous
//
#include <hip/hip_runtime.h>

#define DIMV 16
#define NSTEP 4095      // 4096 - 1 increments
#define NC 64           // chunks
#define TSTEP 64        // chunk length
#define SIG13 4368      // 16 + 256 + 4096
#define L4 65536        // 16^4

// 16-wide register vector as explicit float4s — never runtime-indexed (rule #20).
struct V16 { float4 a, b, c, d; };

#define EACH(OP) OP(a,x) OP(a,y) OP(a,z) OP(a,w) OP(b,x) OP(b,y) OP(b,z) OP(b,w) \
                 OP(c,x) OP(c,y) OP(c,z) OP(c,w) OP(d,x) OP(d,y) OP(d,z) OP(d,w)

__device__ inline V16 ldv16(const float* p) {
    const float4* q = reinterpret_cast<const float4*>(p);
    V16 v; v.a = q[0]; v.b = q[1]; v.c = q[2]; v.d = q[3]; return v;
}
__device__ inline void stv16(float* p, const V16& v) {
    float4* q = reinterpret_cast<float4*>(p);
    q[0] = v.a; q[1] = v.b; q[2] = v.c; q[3] = v.d;
}
__device__ inline V16 zerov16() {
    V16 v; v.a = v.b = v.c = v.d = make_float4(0.f, 0.f, 0.f, 0.f); return v;
}

// ------------- per-chunk LOCAL signature (levels 1-3) + fused dx -------------
// (R12-proven, unchanged)
__global__ __launch_bounds__(256, 1) void k_chunk_sig(const float* __restrict__ x,
                                                      float* __restrict__ dx,
                                                      float* __restrict__ chunk_sig) {
    const int cb = blockIdx.x;
    const int t = threadIdx.x;
    const int ia = t >> 4, ib = t & 15;
    float A1a = 0.f, A2 = 0.f;
    V16 A3 = zerov16();

    const int s0 = cb * TSTEP;
    const int s1 = (s0 + TSTEP < NSTEP) ? (s0 + TSTEP) : NSTEP;

    const float* r0 = x + (size_t)s0 * DIMV;
    const float* r1 = x + (size_t)(s0 + 1) * DIMV;
    V16 xprev = ldv16(r0);
    float xpa = r0[ia], xpb = r0[ib];
    V16 xcur = ldv16(r1);
    float xca = r1[ia], xcb = r1[ib];

    for (int s = s0; s < s1; ++s) {
        int sp = (s + 2 <= NSTEP) ? (s + 2) : NSTEP;
        const float* rn = x + (size_t)sp * DIMV;
        V16 xnext = ldv16(rn);
        float xna = rn[ia], xnb = rn[ib];

        V16 dxv;
#define SB(Q,C) dxv.Q.C = xcur.Q.C - xprev.Q.C;
        EACH(SB)
#undef SB
        float dxa = xca - xpa;
        float dxb = xcb - xpb;
        stv16(dx + (size_t)s * DIMV, dxv);

        float V2 = fmaf(dxb, fmaf(dxa, 1.f/6.f, 0.5f * A1a), A2);
        float h2 = fmaf(dxa, 0.5f, A1a);
#define CS(Q,C) A3.Q.C = fmaf(dxv.Q.C, V2, A3.Q.C);
        EACH(CS)
#undef CS
        A2 = fmaf(dxb, h2, A2);
        A1a += dxa;

        xprev = xcur; xpa = xca; xpb = xcb;
        xcur = xnext; xca = xna; xcb = xnb;
    }
    float* o = chunk_sig + (size_t)cb * SIG13;
    if (ib == 0) o[ia] = A1a;
    o[16 + t] = A2;
    stv16(o + 272 + t * 16, A3);
}

// ------------- fused cascaded prefix (levels 1,2,3) -------------
// (R12-proven, unchanged)
__global__ __launch_bounds__(256, 1) void k_prefixB(const float* __restrict__ chunk_sig,
                                                    float* __restrict__ prefix_sig,
                                                    float* __restrict__ out13) {
    __shared__ float s1s[NC][16];
    __shared__ float p1s[NC][16];
    __shared__ float p2s[NC][16];
    const int a = blockIdx.x;
    const int t = threadIdx.x;

    for (int base = 0; base < NC; base += 16) {
        int c = base + (t >> 4);
        s1s[c][t & 15] = chunk_sig[(size_t)c * SIG13 + (t & 15)];
    }
    __syncthreads();
    if (t < 16) {
        float p = 0.f;
        for (int c = 0; c < NC; ++c) {
            p1s[c][t] = p;
            if (a == 0) prefix_sig[(size_t)c * SIG13 + t] = p;
            p += s1s[c][t];
        }
        if (a == 0) out13[t] = p;
    }
    __syncthreads();
    {
        const int aa = t >> 4, bb = t & 15;
        float pl0 = chunk_sig[0ul * SIG13 + 16 + t];
        float pl1 = chunk_sig[1ul * SIG13 + 16 + t];
        float pl2 = chunk_sig[2ul * SIG13 + 16 + t];
        float pl3 = chunk_sig[3ul * SIG13 + 16 + t];
        float pl4 = chunk_sig[4ul * SIG13 + 16 + t];
        float pl5 = chunk_sig[5ul * SIG13 + 16 + t];
        float pl6 = chunk_sig[6ul * SIG13 + 16 + t];
        float pl7 = chunk_sig[7ul * SIG13 + 16 + t];
        float p = 0.f;
        for (int cb2 = 0; cb2 < NC; cb2 += 8) {
#define STEP2(J) { int c = cb2 + J; \
            if (aa == a) p2s[c][bb] = p; \
            if (a == 0) prefix_sig[(size_t)c * SIG13 + 16 + t] = p; \
            p = fmaf(p1s[c][aa], s1s[c][bb], p + pl##J); \
            int cn = c + 8; \
            if (cn < NC) pl##J = chunk_sig[(size_t)cn * SIG13 + 16 + t]; }
            STEP2(0) STEP2(1) STEP2(2) STEP2(3) STEP2(4) STEP2(5) STEP2(6) STEP2(7)
#undef STEP2
        }
        if (a == 0) out13[16 + t] = p;
    }
    __syncthreads();
    {
        const int c3 = t & 15, k = t >> 4;
        const size_t off3 = 272 + (size_t)a * 256 + t;
#define LD3(J, C) \
        float l3_##J = chunk_sig[(size_t)(C) * SIG13 + off3]; \
        float l2_##J = chunk_sig[(size_t)(C) * SIG13 + 16 + t];
        LD3(0,0) LD3(1,1) LD3(2,2) LD3(3,3) LD3(4,4) LD3(5,5) LD3(6,6) LD3(7,7)
#undef LD3
        float p = 0.f;
        for (int cb2 = 0; cb2 < NC; cb2 += 8) {
#define STEP3(J) { int c = cb2 + J; \
            prefix_sig[(size_t)c * SIG13 + off3] = p; \
            p = p + l3_##J + fmaf(p1s[c][a], l2_##J, p2s[c][k] * s1s[c][c3]); \
            int cn = c + 8; \
            if (cn < NC) { \
                l3_##J = chunk_sig[(size_t)cn * SIG13 + off3]; \
                l2_##J = chunk_sig[(size_t)cn * SIG13 + 16 + t]; } }
            STEP3(0) STEP3(1) STEP3(2) STEP3(3) STEP3(4) STEP3(5) STEP3(6) STEP3(7)
#undef STEP3
        }
        out13[off3] = p;
    }
}

// ------------- level-4 accumulation: j-pair split, LDS-staged dx -------------
// block (cb, h): chunk cb (64 steps), j-pair h. The whole 4 KB dx chunk is
// staged into LDS with one coalesced burst; the recurrence then runs from LDS
// (wave-uniform row reads = broadcast, no global latency in the loop).
__global__ void k_scan4(const float* __restrict__ dx,
                        const float* __restrict__ prefix_sig,
                        float* __restrict__ dst) {
    __shared__ float sdx[TSTEP * DIMV];   // 4 KB
    const int cb = blockIdx.x;   // 0..NC-1
    const int h = blockIdx.y;    // 0..7 : j-pair
    const int t = threadIdx.x;
    const int ia = t >> 4, ib = t & 15;

    const int s0 = cb * TSTEP;
    const int s1 = (s0 + TSTEP < NSTEP) ? (s0 + TSTEP) : NSTEP;
    const int nrow = s1 - s0;               // 64 (63 for last chunk)

    // ---- stage chunk into LDS: 1024 float4 slots, coalesced ----
    {
        const float4* src = reinterpret_cast<const float4*>(dx + (size_t)s0 * DIMV);
        float4* sd4 = reinterpret_cast<float4*>(sdx);
        const int nslot = nrow * (DIMV / 4);
#pragma unroll
        for (int k = 0; k < 4; ++k) {
            int slot = t + 256 * k;
            if (slot < nslot) sd4[slot] = src[slot];
        }
    }
    __syncthreads();

    const float* P = prefix_sig + (size_t)cb * SIG13;
    float A1a = P[ia];
    float A2 = P[16 + t];
    float2 A3p = *reinterpret_cast<const float2*>(P + 272 + t * 16 + h * 2);
    V16 ac0 = zerov16(), ac1 = zerov16();

#pragma unroll 2
    for (int si = 0; si < nrow; ++si) {
        const float* row = sdx + si * DIMV;
        V16 cur = ldv16(row);               // wave-uniform -> LDS broadcast
        float ca = row[ia];
        float cbv = row[ib];
        float2 cj = *reinterpret_cast<const float2*>(row + h * 2);

        float U2 = fmaf(cbv, fmaf(ca, 1.f/24.f, A1a * (1.f/6.f)), 0.5f * A2);
        float V2 = fmaf(cbv, fmaf(ca, 1.f/6.f, A1a * 0.5f), A2);
        float h2 = fmaf(ca, 0.5f, A1a);
        float u30 = fmaf(cj.x, U2, A3p.x);
        float u31 = fmaf(cj.y, U2, A3p.y);
#define AC(Q,C) { ac0.Q.C = fmaf(u30, cur.Q.C, ac0.Q.C); \
                  ac1.Q.C = fmaf(u31, cur.Q.C, ac1.Q.C); }
        EACH(AC)
#undef AC
        A3p.x = fmaf(cj.x, V2, A3p.x);
        A3p.y = fmaf(cj.y, V2, A3p.y);
        A2 = fmaf(cbv, h2, A2);
        A1a += ca;
    }

    float* o = dst + (size_t)cb * L4 + t * 256 + (h * 2) * 16;
    stv16(o, ac0);
    stv16(o + 16, ac1);
}

// ------------- atomic fallback (separate plain kernel; only if ws too small) ----
__global__ void k_scan4_atomic(const float* __restrict__ dx,
                               const float* __restrict__ prefix_sig,
                               float* __restrict__ dst) {
    __shared__ float sdx[TSTEP * DIMV];
    const int cb = blockIdx.x;
    const int h = blockIdx.y;
    const int t = threadIdx.x;
    const int ia = t >> 4, ib = t & 15;

    const int s0 = cb * TSTEP;
    const int s1 = (s0 + TSTEP < NSTEP) ? (s0 + TSTEP) : NSTEP;
    const int nrow = s1 - s0;

    {
        const float4* src = reinterpret_cast<const float4*>(dx + (size_t)s0 * DIMV);
        float4* sd4 = reinterpret_cast<float4*>(sdx);
        const int nslot = nrow * (DIMV / 4);
#pragma unroll
        for (int k = 0; k < 4; ++k) {
            int slot = t + 256 * k;
            if (slot < nslot) sd4[slot] = src[slot];
        }
    }
    __syncthreads();

    const float* P = prefix_sig + (size_t)cb * SIG13;
    float A1a = P[ia];
    float A2 = P[16 + t];
    float2 A3p = *reinterpret_cast<const float2*>(P + 272 + t * 16 + h * 2);
    V16 ac0 = zerov16(), ac1 = zerov16();

    for (int si = 0; si < nrow; ++si) {
        const float* row = sdx + si * DIMV;
        V16 cur = ldv16(row);
        float ca = row[ia];
        float cbv = row[ib];
        float2 cj = *reinterpret_cast<const float2*>(row + h * 2);

        float U2 = fmaf(cbv, fmaf(ca, 1.f/24.f, A1a * (1.f/6.f)), 0.5f * A2);
        float V2 = fmaf(cbv, fmaf(ca, 1.f/6.f, A1a * 0.5f), A2);
        float h2 = fmaf(ca, 0.5f, A1a);
        float u30 = fmaf(cj.x, U2, A3p.x);
        float u31 = fmaf(cj.y, U2, A3p.y);
#define AC(Q,C) { ac0.Q.C = fmaf(u30, cur.Q.C, ac0.Q.C); \
                  ac1.Q.C = fmaf(u31, cur.Q.C, ac1.Q.C); }
        EACH(AC)
#undef AC
        A3p.x = fmaf(cj.x, V2, A3p.x);
        A3p.y = fmaf(cj.y, V2, A3p.y);
        A2 = fmaf(cbv, h2, A2);
        A1a += ca;
    }

    float* o = dst + t * 256 + (h * 2) * 16;
#define STA(Q,C,K) atomicAdd(o + (K), ac0.Q.C); atomicAdd(o + 16 + (K), ac1.Q.C);
    STA(a,x,0) STA(a,y,1) STA(a,z,2) STA(a,w,3)
    STA(b,x,4) STA(b,y,5) STA(b,z,6) STA(b,w,7)
    STA(c,x,8) STA(c,y,9) STA(c,z,10) STA(c,w,11)
    STA(d,x,12) STA(d,y,13) STA(d,z,14) STA(d,w,15)
#undef STA
}

// ------------- sum per-chunk level-4 partials (float2, 128 blocks) -------------
__global__ __launch_bounds__(256) void k_reduce4(const float* __restrict__ partials,
                                                 float* __restrict__ out4) {
    const int i2 = blockIdx.x * 256 + threadIdx.x;  // 0..32767 float2 slots
    const float2* p2 = reinterpret_cast<const float2*>(partials);
    float2 s = make_float2(0.f, 0.f);
#pragma unroll 8
    for (int c = 0; c < NC; ++c) {
        float2 v = p2[(size_t)c * (L4 / 2) + i2];
        s.x += v.x; s.y += v.y;
    }
    reinterpret_cast<float2*>(out4)[i2] = s;
}

extern "C" void kernel_launch(void* const* d_in, const int* in_sizes, int n_in,
                              void* d_out, int out_size, void* d_ws, size_t ws_size,
                              hipStream_t stream) {
    const float* x = (const float*)d_in[0];
    float* out = (float*)d_out;
    float* ws = (float*)d_ws;

    float* dx = ws;                                     // 65536 floats
    float* chunk_sig = ws + 65536;                      // NC * SIG13
    float* prefix_sig = chunk_sig + (size_t)NC * SIG13; // NC * SIG13
    float* partials = prefix_sig + (size_t)NC * SIG13;  // NC * L4
    const size_t need_bytes =
        ((size_t)65536 + 2ull * NC * SIG13 + (size_t)NC * L4) * sizeof(float);

    k_chunk_sig<<<dim3(NC), dim3(256), 0, stream>>>(x, dx, chunk_sig);
    k_prefixB<<<dim3(16), dim3(256), 0, stream>>>(chunk_sig, prefix_sig, out);

    if (ws_size >= need_bytes) {
        k_scan4<<<dim3(NC, 8), dim3(256), 0, stream>>>(dx, prefix_sig, partials);
        k_reduce4<<<dim3(128), dim3(256), 0, stream>>>(partials, out + SIG13);
    } else {
        hipMemsetAsync(out + SIG13, 0, (size_t)L4 * sizeof(float), stream);
        k_scan4_atomic<<<dim3(NC, 8), dim3(256), 0, stream>>>(dx, prefix_sig,
                                                              out + SIG13);
    }
}

// Round 18
// 54.977 us; speedup vs baseline: 1.3331x; 1.0883x over previous
//
#include <hip/hip_runtime.h>

#define DIMV 16
#define NSTEP 4095      // 4096 - 1 increments
#define NC 64           // chunks
#define TSTEP 64        // chunk length
#define SIG13 4368      // 16 + 256 + 4096
#define L4 65536        // 16^4

// 16-wide register vector as explicit float4s — never runtime-indexed (rule #20).
struct V16 { float4 a, b, c, d; };

#define EACH(OP) OP(a,x) OP(a,y) OP(a,z) OP(a,w) OP(b,x) OP(b,y) OP(b,z) OP(b,w) \
                 OP(c,x) OP(c,y) OP(c,z) OP(c,w) OP(d,x) OP(d,y) OP(d,z) OP(d,w)

__device__ inline V16 ldv16(const float* p) {
    const float4* q = reinterpret_cast<const float4*>(p);
    V16 v; v.a = q[0]; v.b = q[1]; v.c = q[2]; v.d = q[3]; return v;
}
__device__ inline void stv16(float* p, const V16& v) {
    float4* q = reinterpret_cast<float4*>(p);
    q[0] = v.a; q[1] = v.b; q[2] = v.c; q[3] = v.d;
}
__device__ inline V16 zerov16() {
    V16 v; v.a = v.b = v.c = v.d = make_float4(0.f, 0.f, 0.f, 0.f); return v;
}

// ------------- per-chunk LOCAL signature (levels 1-3) + fused dx, LDS-staged -------------
// Stage the 65-row x-chunk into LDS with one coalesced burst, then run the
// recurrence entirely from LDS (prev row kept in registers).
__global__ __launch_bounds__(256, 1) void k_chunk_sig(const float* __restrict__ x,
                                                      float* __restrict__ dx,
                                                      float* __restrict__ chunk_sig) {
    __shared__ float sx[(TSTEP + 1) * DIMV];   // 4.16 KB
    const int cb = blockIdx.x;
    const int t = threadIdx.x;
    const int ia = t >> 4, ib = t & 15;

    const int s0 = cb * TSTEP;
    const int s1 = (s0 + TSTEP < NSTEP) ? (s0 + TSTEP) : NSTEP;
    const int nrow = s1 - s0;                  // dx rows (64; 63 for last chunk)

    // stage x rows s0 .. s0+nrow (nrow+1 rows)
    {
        const float4* src = reinterpret_cast<const float4*>(x + (size_t)s0 * DIMV);
        float4* sd4 = reinterpret_cast<float4*>(sx);
        const int nslot = (nrow + 1) * (DIMV / 4);   // <= 260
        if (t < nslot) sd4[t] = src[t];
        int slot2 = t + 256;
        if (slot2 < nslot) sd4[slot2] = src[slot2];
    }
    __syncthreads();

    float A1a = 0.f, A2 = 0.f;
    V16 A3 = zerov16();

    V16 xprev = ldv16(sx);
    float xpa = sx[ia], xpb = sx[ib];

    for (int si = 0; si < nrow; ++si) {
        const float* nrowp = sx + (si + 1) * DIMV;
        V16 xcur = ldv16(nrowp);               // wave-uniform -> LDS broadcast
        float xca = nrowp[ia];
        float xcb = nrowp[ib];

        V16 dxv;
#define SB(Q,C) dxv.Q.C = xcur.Q.C - xprev.Q.C;
        EACH(SB)
#undef SB
        float dxa = xca - xpa;
        float dxb = xcb - xpb;
        stv16(dx + (size_t)(s0 + si) * DIMV, dxv);

        float V2 = fmaf(dxb, fmaf(dxa, 1.f/6.f, 0.5f * A1a), A2);
        float h2 = fmaf(dxa, 0.5f, A1a);
#define CS(Q,C) A3.Q.C = fmaf(dxv.Q.C, V2, A3.Q.C);
        EACH(CS)
#undef CS
        A2 = fmaf(dxb, h2, A2);
        A1a += dxa;

        xprev = xcur; xpa = xca; xpb = xcb;
    }
    float* o = chunk_sig + (size_t)cb * SIG13;
    if (ib == 0) o[ia] = A1a;
    o[16 + t] = A2;
    stv16(o + 272 + t * 16, A3);
}

// ------------- fused cascaded prefix (levels 1,2,3) -------------
// (R12-proven, unchanged)
__global__ __launch_bounds__(256, 1) void k_prefixB(const float* __restrict__ chunk_sig,
                                                    float* __restrict__ prefix_sig,
                                                    float* __restrict__ out13) {
    __shared__ float s1s[NC][16];
    __shared__ float p1s[NC][16];
    __shared__ float p2s[NC][16];
    const int a = blockIdx.x;
    const int t = threadIdx.x;

    for (int base = 0; base < NC; base += 16) {
        int c = base + (t >> 4);
        s1s[c][t & 15] = chunk_sig[(size_t)c * SIG13 + (t & 15)];
    }
    __syncthreads();
    if (t < 16) {
        float p = 0.f;
        for (int c = 0; c < NC; ++c) {
            p1s[c][t] = p;
            if (a == 0) prefix_sig[(size_t)c * SIG13 + t] = p;
            p += s1s[c][t];
        }
        if (a == 0) out13[t] = p;
    }
    __syncthreads();
    {
        const int aa = t >> 4, bb = t & 15;
        float pl0 = chunk_sig[0ul * SIG13 + 16 + t];
        float pl1 = chunk_sig[1ul * SIG13 + 16 + t];
        float pl2 = chunk_sig[2ul * SIG13 + 16 + t];
        float pl3 = chunk_sig[3ul * SIG13 + 16 + t];
        float pl4 = chunk_sig[4ul * SIG13 + 16 + t];
        float pl5 = chunk_sig[5ul * SIG13 + 16 + t];
        float pl6 = chunk_sig[6ul * SIG13 + 16 + t];
        float pl7 = chunk_sig[7ul * SIG13 + 16 + t];
        float p = 0.f;
        for (int cb2 = 0; cb2 < NC; cb2 += 8) {
#define STEP2(J) { int c = cb2 + J; \
            if (aa == a) p2s[c][bb] = p; \
            if (a == 0) prefix_sig[(size_t)c * SIG13 + 16 + t] = p; \
            p = fmaf(p1s[c][aa], s1s[c][bb], p + pl##J); \
            int cn = c + 8; \
            if (cn < NC) pl##J = chunk_sig[(size_t)cn * SIG13 + 16 + t]; }
            STEP2(0) STEP2(1) STEP2(2) STEP2(3) STEP2(4) STEP2(5) STEP2(6) STEP2(7)
#undef STEP2
        }
        if (a == 0) out13[16 + t] = p;
    }
    __syncthreads();
    {
        const int c3 = t & 15, k = t >> 4;
        const size_t off3 = 272 + (size_t)a * 256 + t;
#define LD3(J, C) \
        float l3_##J = chunk_sig[(size_t)(C) * SIG13 + off3]; \
        float l2_##J = chunk_sig[(size_t)(C) * SIG13 + 16 + t];
        LD3(0,0) LD3(1,1) LD3(2,2) LD3(3,3) LD3(4,4) LD3(5,5) LD3(6,6) LD3(7,7)
#undef LD3
        float p = 0.f;
        for (int cb2 = 0; cb2 < NC; cb2 += 8) {
#define STEP3(J) { int c = cb2 + J; \
            prefix_sig[(size_t)c * SIG13 + off3] = p; \
            p = p + l3_##J + fmaf(p1s[c][a], l2_##J, p2s[c][k] * s1s[c][c3]); \
            int cn = c + 8; \
            if (cn < NC) { \
                l3_##J = chunk_sig[(size_t)cn * SIG13 + off3]; \
                l2_##J = chunk_sig[(size_t)cn * SIG13 + 16 + t]; } }
            STEP3(0) STEP3(1) STEP3(2) STEP3(3) STEP3(4) STEP3(5) STEP3(6) STEP3(7)
#undef STEP3
        }
        out13[off3] = p;
    }
}

// ------------- level-4 accumulation: j-pair split, LDS-staged dx -------------
// R17 body + __launch_bounds__(256,1): without bounds hipcc assumes 1024-thread
// blocks and caps VGPR at 64 -> silent spill (the ~30 us mystery of R16/R17).
__global__ __launch_bounds__(256, 1) void k_scan4(const float* __restrict__ dx,
                                                  const float* __restrict__ prefix_sig,
                                                  float* __restrict__ dst) {
    __shared__ float sdx[TSTEP * DIMV];   // 4 KB
    const int cb = blockIdx.x;   // 0..NC-1
    const int h = blockIdx.y;    // 0..7 : j-pair
    const int t = threadIdx.x;
    const int ia = t >> 4, ib = t & 15;

    const int s0 = cb * TSTEP;
    const int s1 = (s0 + TSTEP < NSTEP) ? (s0 + TSTEP) : NSTEP;
    const int nrow = s1 - s0;               // 64 (63 for last chunk)

    // ---- stage chunk into LDS: coalesced burst ----
    {
        const float4* src = reinterpret_cast<const float4*>(dx + (size_t)s0 * DIMV);
        float4* sd4 = reinterpret_cast<float4*>(sdx);
        const int nslot = nrow * (DIMV / 4);
#pragma unroll
        for (int k = 0; k < 4; ++k) {
            int slot = t + 256 * k;
            if (slot < nslot) sd4[slot] = src[slot];
        }
    }
    __syncthreads();

    const float* P = prefix_sig + (size_t)cb * SIG13;
    float A1a = P[ia];
    float A2 = P[16 + t];
    float2 A3p = *reinterpret_cast<const float2*>(P + 272 + t * 16 + h * 2);
    V16 ac0 = zerov16(), ac1 = zerov16();

#pragma unroll 2
    for (int si = 0; si < nrow; ++si) {
        const float* row = sdx + si * DIMV;
        V16 cur = ldv16(row);               // wave-uniform -> LDS broadcast
        float ca = row[ia];
        float cbv = row[ib];
        float2 cj = *reinterpret_cast<const float2*>(row + h * 2);

        float U2 = fmaf(cbv, fmaf(ca, 1.f/24.f, A1a * (1.f/6.f)), 0.5f * A2);
        float V2 = fmaf(cbv, fmaf(ca, 1.f/6.f, A1a * 0.5f), A2);
        float h2 = fmaf(ca, 0.5f, A1a);
        float u30 = fmaf(cj.x, U2, A3p.x);
        float u31 = fmaf(cj.y, U2, A3p.y);
#define AC(Q,C) { ac0.Q.C = fmaf(u30, cur.Q.C, ac0.Q.C); \
                  ac1.Q.C = fmaf(u31, cur.Q.C, ac1.Q.C); }
        EACH(AC)
#undef AC
        A3p.x = fmaf(cj.x, V2, A3p.x);
        A3p.y = fmaf(cj.y, V2, A3p.y);
        A2 = fmaf(cbv, h2, A2);
        A1a += ca;
    }

    float* o = dst + (size_t)cb * L4 + t * 256 + (h * 2) * 16;
    stv16(o, ac0);
    stv16(o + 16, ac1);
}

// ------------- atomic fallback (only if ws too small) -------------
__global__ __launch_bounds__(256, 1) void k_scan4_atomic(const float* __restrict__ dx,
                                                         const float* __restrict__ prefix_sig,
                                                         float* __restrict__ dst) {
    __shared__ float sdx[TSTEP * DIMV];
    const int cb = blockIdx.x;
    const int h = blockIdx.y;
    const int t = threadIdx.x;
    const int ia = t >> 4, ib = t & 15;

    const int s0 = cb * TSTEP;
    const int s1 = (s0 + TSTEP < NSTEP) ? (s0 + TSTEP) : NSTEP;
    const int nrow = s1 - s0;

    {
        const float4* src = reinterpret_cast<const float4*>(dx + (size_t)s0 * DIMV);
        float4* sd4 = reinterpret_cast<float4*>(sdx);
        const int nslot = nrow * (DIMV / 4);
#pragma unroll
        for (int k = 0; k < 4; ++k) {
            int slot = t + 256 * k;
            if (slot < nslot) sd4[slot] = src[slot];
        }
    }
    __syncthreads();

    const float* P = prefix_sig + (size_t)cb * SIG13;
    float A1a = P[ia];
    float A2 = P[16 + t];
    float2 A3p = *reinterpret_cast<const float2*>(P + 272 + t * 16 + h * 2);
    V16 ac0 = zerov16(), ac1 = zerov16();

    for (int si = 0; si < nrow; ++si) {
        const float* row = sdx + si * DIMV;
        V16 cur = ldv16(row);
        float ca = row[ia];
        float cbv = row[ib];
        float2 cj = *reinterpret_cast<const float2*>(row + h * 2);

        float U2 = fmaf(cbv, fmaf(ca, 1.f/24.f, A1a * (1.f/6.f)), 0.5f * A2);
        float V2 = fmaf(cbv, fmaf(ca, 1.f/6.f, A1a * 0.5f), A2);
        float h2 = fmaf(ca, 0.5f, A1a);
        float u30 = fmaf(cj.x, U2, A3p.x);
        float u31 = fmaf(cj.y, U2, A3p.y);
#define AC(Q,C) { ac0.Q.C = fmaf(u30, cur.Q.C, ac0.Q.C); \
                  ac1.Q.C = fmaf(u31, cur.Q.C, ac1.Q.C); }
        EACH(AC)
#undef AC
        A3p.x = fmaf(cj.x, V2, A3p.x);
        A3p.y = fmaf(cj.y, V2, A3p.y);
        A2 = fmaf(cbv, h2, A2);
        A1a += ca;
    }

    float* o = dst + t * 256 + (h * 2) * 16;
#define STA(Q,C,K) atomicAdd(o + (K), ac0.Q.C); atomicAdd(o + 16 + (K), ac1.Q.C);
    STA(a,x,0) STA(a,y,1) STA(a,z,2) STA(a,w,3)
    STA(b,x,4) STA(b,y,5) STA(b,z,6) STA(b,w,7)
    STA(c,x,8) STA(c,y,9) STA(c,z,10) STA(c,w,11)
    STA(d,x,12) STA(d,y,13) STA(d,z,14) STA(d,w,15)
#undef STA
}

// ------------- sum per-chunk level-4 partials (float2, 128 blocks) -------------
__global__ __launch_bounds__(256) void k_reduce4(const float* __restrict__ partials,
                                                 float* __restrict__ out4) {
    const int i2 = blockIdx.x * 256 + threadIdx.x;  // 0..32767 float2 slots
    const float2* p2 = reinterpret_cast<const float2*>(partials);
    float2 s = make_float2(0.f, 0.f);
#pragma unroll 8
    for (int c = 0; c < NC; ++c) {
        float2 v = p2[(size_t)c * (L4 / 2) + i2];
        s.x += v.x; s.y += v.y;
    }
    reinterpret_cast<float2*>(out4)[i2] = s;
}

extern "C" void kernel_launch(void* const* d_in, const int* in_sizes, int n_in,
                              void* d_out, int out_size, void* d_ws, size_t ws_size,
                              hipStream_t stream) {
    const float* x = (const float*)d_in[0];
    float* out = (float*)d_out;
    float* ws = (float*)d_ws;

    float* dx = ws;                                     // 65536 floats
    float* chunk_sig = ws + 65536;                      // NC * SIG13
    float* prefix_sig = chunk_sig + (size_t)NC * SIG13; // NC * SIG13
    float* partials = prefix_sig + (size_t)NC * SIG13;  // NC * L4
    const size_t need_bytes =
        ((size_t)65536 + 2ull * NC * SIG13 + (size_t)NC * L4) * sizeof(float);

    k_chunk_sig<<<dim3(NC), dim3(256), 0, stream>>>(x, dx, chunk_sig);
    k_prefixB<<<dim3(16), dim3(256), 0, stream>>>(chunk_sig, prefix_sig, out);

    if (ws_size >= need_bytes) {
        k_scan4<<<dim3(NC, 8), dim3(256), 0, stream>>>(dx, prefix_sig, partials);
        k_reduce4<<<dim3(128), dim3(256), 0, stream>>>(partials, out + SIG13);
    } else {
        hipMemsetAsync(out + SIG13, 0, (size_t)L4 * sizeof(float), stream);
        k_scan4_atomic<<<dim3(NC, 8), dim3(256), 0, stream>>>(dx, prefix_sig,
                                                              out + SIG13);
    }
}